// Round 5
// baseline (218.094 us; speedup 1.0000x reference)
//
#include <hip/hip_runtime.h>
#include <hip/hip_cooperative_groups.h>
#include <math.h>

namespace cg = cooperative_groups;

namespace {

constexpr int NG     = 2048;
constexpr int IMG_H  = 160;
constexpr int IMG_W  = 224;
constexpr int HW     = IMG_H * IMG_W;   // 35840
constexpr int TS     = 8;               // tile size (8x8 px)
constexpr int TX     = IMG_W / TS;      // 28
constexpr int TYN    = IMG_H / TS;      // 20
constexpr int NTILE  = TX * TYN;        // 560

constexpr int NSEG   = 4;               // one depth segment per wave
constexpr int SEGS   = NG / NSEG;       // 512 slots per segment

constexpr float TFX   = 0.5774f;
constexpr float TFY   = (float)(0.5774 * 160.0 / 224.0);
constexpr float FXC   = (float)(224.0 / (2.0 * 0.5774));
constexpr float FYC   = (float)(160.0 / (2.0 * (0.5774 * 160.0 / 224.0)));
constexpr float LIMX  = (float)(1.3 * 0.5774);
constexpr float LIMY  = (float)(1.3 * (0.5774 * 160.0 / 224.0));
constexpr float A_MIN = (float)(1.0 / 255.0);
constexpr float NEARP = 0.2f;
constexpr float LOWPASS = 0.3f;
constexpr float L2E   = 1.4426950408889634f;   // log2(e)
constexpr float LN2   = 0.6931471805599453f;
constexpr float L2_255 = 7.994353436858858f;   // log2(255)

// output float offsets (flat, in return order)
constexpr int O_COLOR = 0;
constexpr int O_RADII = 3 * HW;           // 107520
constexpr int O_DEPTH = O_RADII + NG;     // 109568
constexpr int O_OPAC  = O_DEPTH + HW;     // 145408
constexpr int O_NT    = O_OPAC + HW;      // 181248

// workspace offsets (float/int units)
// AoS record (12 floats): [0]px [1]py [2]dxm [3]dym | [4]h0 [5]h1 [6]h2 [7]l2op | [8]r [9]g [10]b [11]dep
constexpr int W_U    = 0;          // unsorted AoS, NG*12 floats
constexpr int W_KEY  = 12 * NG;    // depth keys, NG floats
constexpr int W_UPB  = 13 * NG;    // unsorted packed tile bbox, NG uints
constexpr int W_S    = 14 * NG;    // sorted AoS, NG*12 floats
constexpr int W_ORG  = 26 * NG;    // int: original index per sorted slot
constexpr int W_PB   = 27 * NG;    // sorted packed tile bbox, NG uints

} // namespace

__global__ __launch_bounds__(256) void k_fused(const float* __restrict__ means3D,
                                               const float* __restrict__ opac,
                                               const float* __restrict__ cols,
                                               const float* __restrict__ scales,
                                               const float* __restrict__ rots,
                                               const float* __restrict__ vm,
                                               const float* __restrict__ bg,
                                               float* __restrict__ wsf,
                                               int* __restrict__ wsi,
                                               unsigned* __restrict__ wsu,
                                               float* __restrict__ out)
{
    __shared__ float skbuf[NG];           // 8 KB: keys (phase 2), Lcnt (phase 3)
    __shared__ int   Llist[NSEG][SEGS];   // 8 KB
    __shared__ float Ls[NSEG][64][12];    // 12 KB
    __shared__ float Lpart[NSEG][5][64];  // 5 KB

    cg::grid_group grid = cg::this_grid();

    int blk  = blockIdx.x;
    int tid  = threadIdx.x;
    int lane = tid & 63;
    int wv   = tid >> 6;

    // ================= phase 1: per-gaussian preprocess =================
    // gaussian i = blk + 560*t, handled by threads t=0..3 of each block
    if (tid < 4) {
        int i = blk + NTILE * tid;
        if (i < NG) {
            out[O_NT + i] = 0.0f;

            float R00 = vm[0], R01 = vm[1], R02 = vm[2],  T0 = vm[3];
            float R10 = vm[4], R11 = vm[5], R12 = vm[6],  T1 = vm[7];
            float R20 = vm[8], R21 = vm[9], R22 = vm[10], T2 = vm[11];

            float mx = means3D[3*i], my = means3D[3*i+1], mz = means3D[3*i+2];
            float tx = R00*mx + R01*my + R02*mz + T0;
            float ty = R10*mx + R11*my + R12*mz + T1;
            float tz = R20*mx + R21*my + R22*mz + T2;

            float txz = fminf(LIMX, fmaxf(-LIMX, tx / tz)) * tz;
            float tyz = fminf(LIMY, fmaxf(-LIMY, ty / tz)) * tz;

            float qw = rots[4*i], qx = rots[4*i+1], qy = rots[4*i+2], qz = rots[4*i+3];
            float qn = 1.0f / sqrtf(qw*qw + qx*qx + qy*qy + qz*qz);
            qw *= qn; qx *= qn; qy *= qn; qz *= qn;
            float r00 = 1.0f - 2.0f*(qy*qy + qz*qz), r01 = 2.0f*(qx*qy - qw*qz), r02 = 2.0f*(qx*qz + qw*qy);
            float r10 = 2.0f*(qx*qy + qw*qz), r11 = 1.0f - 2.0f*(qx*qx + qz*qz), r12 = 2.0f*(qy*qz - qw*qx);
            float r20 = 2.0f*(qx*qz - qw*qy), r21 = 2.0f*(qy*qz + qw*qx), r22 = 1.0f - 2.0f*(qx*qx + qy*qy);

            float s0 = scales[3*i];   s0 = s0 * s0;
            float s1 = scales[3*i+1]; s1 = s1 * s1;
            float s2 = scales[3*i+2]; s2 = s2 * s2;

            float S00 = r00*r00*s0 + r01*r01*s1 + r02*r02*s2;
            float S01 = r00*r10*s0 + r01*r11*s1 + r02*r12*s2;
            float S02 = r00*r20*s0 + r01*r21*s1 + r02*r22*s2;
            float S11 = r10*r10*s0 + r11*r11*s1 + r12*r12*s2;
            float S12 = r10*r20*s0 + r11*r21*s1 + r12*r22*s2;
            float S22 = r20*r20*s0 + r21*r21*s1 + r22*r22*s2;

            float j00 = FXC / tz;
            float j02 = -FXC * txz / (tz * tz);
            float j11 = FYC / tz;
            float j12 = -FYC * tyz / (tz * tz);

            float Tm00 = j00*R00 + j02*R20, Tm01 = j00*R01 + j02*R21, Tm02 = j00*R02 + j02*R22;
            float Tm10 = j11*R10 + j12*R20, Tm11 = j11*R11 + j12*R21, Tm12 = j11*R12 + j12*R22;

            float M00 = Tm00*S00 + Tm01*S01 + Tm02*S02;
            float M01 = Tm00*S01 + Tm01*S11 + Tm02*S12;
            float M02 = Tm00*S02 + Tm01*S12 + Tm02*S22;
            float M10 = Tm10*S00 + Tm11*S01 + Tm12*S02;
            float M11 = Tm10*S01 + Tm11*S11 + Tm12*S12;
            float M12 = Tm10*S02 + Tm11*S12 + Tm12*S22;

            float cov00 = M00*Tm00 + M01*Tm01 + M02*Tm02;
            float cov01 = M00*Tm10 + M01*Tm11 + M02*Tm12;
            float cov11 = M10*Tm10 + M11*Tm11 + M12*Tm12;

            float a = cov00 + LOWPASS;
            float b = cov01;
            float c = cov11 + LOWPASS;
            float det = a*c - b*b;
            float dinv = 1.0f / det;
            float con0 = c * dinv, con1 = -b * dinv, con2 = a * dinv;

            float mid  = 0.5f * (a + c);
            float lam1 = mid + sqrtf(fmaxf(0.1f, mid*mid - det));
            float radf = ceilf(3.0f * sqrtf(lam1));

            float px = ((tx / (tz * TFX) + 1.0f) * (float)IMG_W - 1.0f) * 0.5f;
            float py = ((ty / (tz * TFY) + 1.0f) * (float)IMG_H - 1.0f) * 0.5f;

            bool valid = (tz > NEARP) && (det > 0.0f) && (radf > 0.0f);

            float op   = opac[i];
            float l2op = log2f(op);
            float tlin = fmaxf(0.0f, (l2op + L2_255) * LN2);
            float dxm  = sqrtf(2.0f * tlin * a) * 1.001f + 0.1f;
            float dym  = sqrtf(2.0f * tlin * c) * 1.001f + 0.1f;

            int itx0 = (int)floorf((px - dxm) * (1.0f / TS));
            int itx1 = (int)floorf((px + dxm) * (1.0f / TS));
            int ity0 = (int)floorf((py - dym) * (1.0f / TS));
            int ity1 = (int)floorf((py + dym) * (1.0f / TS));
            unsigned pb;
            if (!valid || itx1 < 0 || ity1 < 0 || itx0 >= TX || ity0 >= TYN) {
                pb = 0xFFFFFFFFu;
            } else {
                unsigned a0 = (unsigned)max(itx0, 0);
                unsigned a1 = (unsigned)max(ity0, 0);
                unsigned a2 = (unsigned)min(itx1, TX - 1);
                unsigned a3 = (unsigned)min(ity1, TYN - 1);
                pb = a0 | (a1 << 8) | (a2 << 16) | (a3 << 24);
            }
            wsu[W_UPB + i] = pb;

            float4 f0, f1, f2;
            if (valid) {
                f0 = make_float4(px, py, dxm, dym);
                f1 = make_float4(-0.5f*con0*L2E, -con1*L2E, -0.5f*con2*L2E, l2op);
                f2 = make_float4(cols[3*i], cols[3*i+1], cols[3*i+2], tz);
            } else {
                f0 = make_float4(1e9f, 1e9f, -1.0f, -1.0f);
                f1 = make_float4(0.0f, 0.0f, 0.0f, -1000.0f);
                f2 = make_float4(0.0f, 0.0f, 0.0f, 0.0f);
            }
            float4* dst = (float4*)&wsf[W_U + i*12];
            dst[0] = f0; dst[1] = f1; dst[2] = f2;
            wsf[W_KEY + i] = valid ? tz : INFINITY;
            out[O_RADII + i] = valid ? radf : 0.0f;
        }
    }

    __threadfence();
    grid.sync();

    // ================= phase 2: rank & scatter =================
    // all 2048 keys -> LDS (stride-256 scalar loads: coalesced global, conflict-free LDS)
    #pragma unroll
    for (int j = 0; j < NG / 256; ++j)
        skbuf[tid + 256 * j] = wsf[W_KEY + tid + 256 * j];
    __syncthreads();

    {
        int i = blk + NTILE * wv;
        if (i < NG) {
            float ki = skbuf[i];
            int r = 0;
            #pragma unroll
            for (int u = 0; u < NG / 64; ++u) {
                int j = lane + 64 * u;           // stride-64: 2 lanes/bank, conflict-free
                float k = skbuf[j];
                r += (k < ki || (k == ki && j < i)) ? 1 : 0;
            }
            r += __shfl_xor(r, 1);
            r += __shfl_xor(r, 2);
            r += __shfl_xor(r, 4);
            r += __shfl_xor(r, 8);
            r += __shfl_xor(r, 16);
            r += __shfl_xor(r, 32);

            if (lane == 0) {
                const float4* src = (const float4*)&wsf[W_U + i*12];
                float4 a0 = src[0], a1 = src[1], a2 = src[2];
                float4* dst = (float4*)&wsf[W_S + r*12];
                dst[0] = a0; dst[1] = a1; dst[2] = a2;
                wsu[W_PB + r] = wsu[W_UPB + i];
                wsi[W_ORG + r] = i;
            }
        }
    }

    __threadfence();
    grid.sync();
    __syncthreads();   // skbuf reuse as Lcnt below

    // ================= phase 3: rasterize (wave wv = depth segment wv) =================
    int* Lcnt = (int*)skbuf;   // [NSEG][SEGS]
    int tx = blk % TX, ty = blk / TX;
    int base0 = wv * SEGS;

    // scan this segment's packed tile ranges (coalesced uint loads, ballot-compact)
    int cnt = 0;
    #pragma unroll
    for (int c = 0; c < SEGS / 64; ++c) {
        unsigned w = wsu[W_PB + base0 + c * 64 + lane];
        bool keep = ((w & 255u) <= (unsigned)tx) && ((unsigned)tx <= ((w >> 16) & 255u))
                 && (((w >> 8) & 255u) <= (unsigned)ty) && ((unsigned)ty <= (w >> 24));
        unsigned long long m = __ballot(keep);
        if (keep) Llist[wv][cnt + __popcll(m & ((1ull << lane) - 1ull))] = base0 + c * 64 + lane;
        cnt += (int)__popcll(m);
    }

    // composite: each lane owns one pixel of the 8x8 tile
    int px_i = tx * TS + (lane & 7);
    int py_i = ty * TS + (lane >> 3);
    float gx = (float)px_i, gy = (float)py_i;

    float T = 1.0f, C0 = 0.0f, C1 = 0.0f, C2 = 0.0f, D = 0.0f;

    for (int b2 = 0; b2 < cnt; b2 += 64) {
        int cl = min(64, cnt - b2);
        if (lane < cl) {
            int e = Llist[wv][b2 + lane];
            const float4* s4 = (const float4*)&wsf[W_S + e*12];
            *(float4*)&Ls[wv][lane][0] = s4[0];
            *(float4*)&Ls[wv][lane][4] = s4[1];
            *(float4*)&Ls[wv][lane][8] = s4[2];
        }
        #pragma unroll 2
        for (int g = 0; g < cl; ++g) {
            float4 f0 = *(const float4*)&Ls[wv][g][0];
            float4 f1 = *(const float4*)&Ls[wv][g][4];
            float4 f2 = *(const float4*)&Ls[wv][g][8];
            float dx = f0.x - gx, dy = f0.y - gy;
            float p2 = f1.x*dx*dx + f1.y*dx*dy + f1.z*dy*dy;
            float al = fminf(0.99f, exp2f(p2 + f1.w));
            bool keep = (p2 <= 0.0f) && (al >= A_MIN);
            float a = keep ? al : 0.0f;
            float w = T * a;
            C0 = fmaf(w, f2.x, C0);
            C1 = fmaf(w, f2.y, C1);
            C2 = fmaf(w, f2.z, C2);
            D  = fmaf(w, f2.w, D);
            T -= w;
            unsigned long long m = __ballot(keep);
            if (lane == g) Lcnt[wv * SEGS + b2 + g] = (int)__popcll(m);
        }
    }

    Lpart[wv][0][lane] = T;
    Lpart[wv][1][lane] = C0;
    Lpart[wv][2][lane] = C1;
    Lpart[wv][3][lane] = C2;
    Lpart[wv][4][lane] = D;

    // batched n_touched flush (order-independent exact float atomics)
    for (int j = lane; j < cnt; j += 64) {
        int c = Lcnt[wv * SEGS + j];
        if (c > 0) atomicAdd(out + O_NT + wsi[W_ORG + Llist[wv][j]], (float)c);
    }

    __syncthreads();

    // ================= phase 4: in-block combine (wave 0) =================
    if (wv == 0) {
        float Tt = 1.0f, c0 = 0.0f, c1 = 0.0f, c2 = 0.0f, d = 0.0f;
        #pragma unroll
        for (int s = 0; s < NSEG; ++s) {
            c0 = fmaf(Tt, Lpart[s][1][lane], c0);
            c1 = fmaf(Tt, Lpart[s][2][lane], c1);
            c2 = fmaf(Tt, Lpart[s][3][lane], c2);
            d  = fmaf(Tt, Lpart[s][4][lane], d);
            Tt *= Lpart[s][0][lane];
        }
        int pix = py_i * IMG_W + px_i;
        out[O_COLOR + 0*HW + pix] = c0 + bg[0] * Tt;
        out[O_COLOR + 1*HW + pix] = c1 + bg[1] * Tt;
        out[O_COLOR + 2*HW + pix] = c2 + bg[2] * Tt;
        out[O_DEPTH + pix] = d;
        out[O_OPAC  + pix] = 1.0f - Tt;
    }
}

extern "C" void kernel_launch(void* const* d_in, const int* in_sizes, int n_in,
                              void* d_out, int out_size, void* d_ws, size_t ws_size,
                              hipStream_t stream)
{
    const float* means3D = (const float*)d_in[0];
    // d_in[1] = means2D (unused)
    const float* opac    = (const float*)d_in[2];
    const float* cols    = (const float*)d_in[3];
    const float* scales  = (const float*)d_in[4];
    const float* rots    = (const float*)d_in[5];
    const float* bg      = (const float*)d_in[6];
    const float* vm      = (const float*)d_in[7];
    float* outp = (float*)d_out;
    float* wsf  = (float*)d_ws;
    int*   wsi  = (int*)d_ws;
    unsigned* wsu = (unsigned*)d_ws;

    void* args[] = { (void*)&means3D, (void*)&opac, (void*)&cols, (void*)&scales,
                     (void*)&rots, (void*)&vm, (void*)&bg,
                     (void*)&wsf, (void*)&wsi, (void*)&wsu, (void*)&outp };
    hipLaunchCooperativeKernel((const void*)k_fused, dim3(NTILE), dim3(256),
                               args, 0, stream);
}

// Round 6
// 117.273 us; speedup vs baseline: 1.8597x; 1.8597x over previous
//
#include <hip/hip_runtime.h>
#include <math.h>

namespace {

constexpr int NG     = 2048;
constexpr int IMG_H  = 160;
constexpr int IMG_W  = 224;
constexpr int HW     = IMG_H * IMG_W;   // 35840
constexpr int TS     = 8;               // tile size (8x8 px, 64 threads = 1 wave)
constexpr int TX     = IMG_W / TS;      // 28
constexpr int TYN    = IMG_H / TS;      // 20
constexpr int NTILE  = TX * TYN;        // 560

constexpr int NSEG   = 8;               // depth segments per tile
constexpr int SEGS   = NG / NSEG;       // 256 slots per segment

constexpr int TPG    = 64;              // k_rank: threads per gaussian (full wave)
constexpr int SEGK   = NG / TPG;        // 32 keys per thread

constexpr float TFX   = 0.5774f;
constexpr float TFY   = (float)(0.5774 * 160.0 / 224.0);
constexpr float FXC   = (float)(224.0 / (2.0 * 0.5774));
constexpr float FYC   = (float)(160.0 / (2.0 * (0.5774 * 160.0 / 224.0)));
constexpr float LIMX  = (float)(1.3 * 0.5774);
constexpr float LIMY  = (float)(1.3 * (0.5774 * 160.0 / 224.0));
constexpr float A_MIN = (float)(1.0 / 255.0);
constexpr float NEARP = 0.2f;
constexpr float LOWPASS = 0.3f;
constexpr float L2E   = 1.4426950408889634f;   // log2(e)
constexpr float LN2   = 0.6931471805599453f;
constexpr float L2_255 = 7.994353436858858f;   // log2(255)

// output float offsets (flat, in return order)
constexpr int O_COLOR = 0;
constexpr int O_RADII = 3 * HW;           // 107520
constexpr int O_DEPTH = O_RADII + NG;     // 109568
constexpr int O_OPAC  = O_DEPTH + HW;     // 145408
constexpr int O_NT    = O_OPAC + HW;      // 181248

// workspace offsets (float/int units, both 4B)
// AoS record (12 floats): [0]px [1]py [2]dxm [3]dym | [4]h0 [5]h1 [6]h2 [7]l2op | [8]r [9]g [10]b [11]dep
constexpr int W_U    = 0;          // unsorted AoS, NG*12 floats
constexpr int W_KEY  = 12 * NG;    // depth keys, NG floats
constexpr int W_UPB  = 13 * NG;    // unsorted packed tile bbox, NG uints
constexpr int W_S    = 14 * NG;    // sorted AoS, NG*12 floats
constexpr int W_ORG  = 26 * NG;    // int: original index per sorted slot
constexpr int W_PB   = 27 * NG;    // sorted packed tile bbox, NG uints
constexpr int W_PART = 28 * NG;    // NTILE*NSEG*5*64 floats, per-(tile,seg) partials
constexpr int W_CTR  = W_PART + NTILE * NSEG * 5 * 64;   // NTILE ints, completion counters

} // namespace

__global__ __launch_bounds__(256) void k_pre(const float* __restrict__ means3D,
                                             const float* __restrict__ opac,
                                             const float* __restrict__ cols,
                                             const float* __restrict__ scales,
                                             const float* __restrict__ rots,
                                             const float* __restrict__ vm,
                                             float* __restrict__ wsf,
                                             unsigned* __restrict__ wsu,
                                             int* __restrict__ ctr,
                                             float* __restrict__ out)
{
    int i = blockIdx.x * blockDim.x + threadIdx.x;
    if (i >= NG) return;
    out[O_NT + i] = 0.0f;            // n_touched accumulator (re-zeroed every call)
    if (i < NTILE) ctr[i] = 0;       // per-tile completion counters (re-zeroed every call)

    float R00 = vm[0], R01 = vm[1], R02 = vm[2],  T0 = vm[3];
    float R10 = vm[4], R11 = vm[5], R12 = vm[6],  T1 = vm[7];
    float R20 = vm[8], R21 = vm[9], R22 = vm[10], T2 = vm[11];

    float mx = means3D[3*i], my = means3D[3*i+1], mz = means3D[3*i+2];
    float tx = R00*mx + R01*my + R02*mz + T0;
    float ty = R10*mx + R11*my + R12*mz + T1;
    float tz = R20*mx + R21*my + R22*mz + T2;

    float txz = fminf(LIMX, fmaxf(-LIMX, tx / tz)) * tz;
    float tyz = fminf(LIMY, fmaxf(-LIMY, ty / tz)) * tz;

    float qw = rots[4*i], qx = rots[4*i+1], qy = rots[4*i+2], qz = rots[4*i+3];
    float qn = 1.0f / sqrtf(qw*qw + qx*qx + qy*qy + qz*qz);
    qw *= qn; qx *= qn; qy *= qn; qz *= qn;
    float r00 = 1.0f - 2.0f*(qy*qy + qz*qz), r01 = 2.0f*(qx*qy - qw*qz), r02 = 2.0f*(qx*qz + qw*qy);
    float r10 = 2.0f*(qx*qy + qw*qz), r11 = 1.0f - 2.0f*(qx*qx + qz*qz), r12 = 2.0f*(qy*qz - qw*qx);
    float r20 = 2.0f*(qx*qz - qw*qy), r21 = 2.0f*(qy*qz + qw*qx), r22 = 1.0f - 2.0f*(qx*qx + qy*qy);

    float s0 = scales[3*i];   s0 = s0 * s0;
    float s1 = scales[3*i+1]; s1 = s1 * s1;
    float s2 = scales[3*i+2]; s2 = s2 * s2;

    float S00 = r00*r00*s0 + r01*r01*s1 + r02*r02*s2;
    float S01 = r00*r10*s0 + r01*r11*s1 + r02*r12*s2;
    float S02 = r00*r20*s0 + r01*r21*s1 + r02*r22*s2;
    float S11 = r10*r10*s0 + r11*r11*s1 + r12*r12*s2;
    float S12 = r10*r20*s0 + r11*r21*s1 + r12*r22*s2;
    float S22 = r20*r20*s0 + r21*r21*s1 + r22*r22*s2;

    float j00 = FXC / tz;
    float j02 = -FXC * txz / (tz * tz);
    float j11 = FYC / tz;
    float j12 = -FYC * tyz / (tz * tz);

    float Tm00 = j00*R00 + j02*R20, Tm01 = j00*R01 + j02*R21, Tm02 = j00*R02 + j02*R22;
    float Tm10 = j11*R10 + j12*R20, Tm11 = j11*R11 + j12*R21, Tm12 = j11*R12 + j12*R22;

    float M00 = Tm00*S00 + Tm01*S01 + Tm02*S02;
    float M01 = Tm00*S01 + Tm01*S11 + Tm02*S12;
    float M02 = Tm00*S02 + Tm01*S12 + Tm02*S22;
    float M10 = Tm10*S00 + Tm11*S01 + Tm12*S02;
    float M11 = Tm10*S01 + Tm11*S11 + Tm12*S12;
    float M12 = Tm10*S02 + Tm11*S12 + Tm12*S22;

    float cov00 = M00*Tm00 + M01*Tm01 + M02*Tm02;
    float cov01 = M00*Tm10 + M01*Tm11 + M02*Tm12;
    float cov11 = M10*Tm10 + M11*Tm11 + M12*Tm12;

    float a = cov00 + LOWPASS;
    float b = cov01;
    float c = cov11 + LOWPASS;
    float det = a*c - b*b;
    float dinv = 1.0f / det;
    float con0 = c * dinv, con1 = -b * dinv, con2 = a * dinv;

    float mid  = 0.5f * (a + c);
    float lam1 = mid + sqrtf(fmaxf(0.1f, mid*mid - det));
    float radf = ceilf(3.0f * sqrtf(lam1));

    float px = ((tx / (tz * TFX) + 1.0f) * (float)IMG_W - 1.0f) * 0.5f;
    float py = ((ty / (tz * TFY) + 1.0f) * (float)IMG_H - 1.0f) * 0.5f;

    bool valid = (tz > NEARP) && (det > 0.0f) && (radf > 0.0f);

    float op   = opac[i];
    float l2op = log2f(op);
    // exact alpha-cutoff ellipse: alpha>=1/255 <=> power >= -ln(255*op); bbox half-widths
    float tlin = fmaxf(0.0f, (l2op + L2_255) * LN2);
    float dxm  = sqrtf(2.0f * tlin * a) * 1.001f + 0.1f;
    float dym  = sqrtf(2.0f * tlin * c) * 1.001f + 0.1f;

    // packed conservative tile range (uchar4: tx0, ty0, tx1, ty1)
    int itx0 = (int)floorf((px - dxm) * (1.0f / TS));
    int itx1 = (int)floorf((px + dxm) * (1.0f / TS));
    int ity0 = (int)floorf((py - dym) * (1.0f / TS));
    int ity1 = (int)floorf((py + dym) * (1.0f / TS));
    unsigned pb;
    if (!valid || itx1 < 0 || ity1 < 0 || itx0 >= TX || ity0 >= TYN) {
        pb = 0xFFFFFFFFu;   // empty: tx0=255 never <= tx
    } else {
        unsigned a0 = (unsigned)max(itx0, 0);
        unsigned a1 = (unsigned)max(ity0, 0);
        unsigned a2 = (unsigned)min(itx1, TX - 1);
        unsigned a3 = (unsigned)min(ity1, TYN - 1);
        pb = a0 | (a1 << 8) | (a2 << 16) | (a3 << 24);
    }
    wsu[W_UPB + i] = pb;

    float4 f0, f1, f2;
    if (valid) {
        f0 = make_float4(px, py, dxm, dym);
        f1 = make_float4(-0.5f*con0*L2E, -con1*L2E, -0.5f*con2*L2E, l2op);
        f2 = make_float4(cols[3*i], cols[3*i+1], cols[3*i+2], tz);
    } else {
        f0 = make_float4(1e9f, 1e9f, -1.0f, -1.0f);
        f1 = make_float4(0.0f, 0.0f, 0.0f, -1000.0f);
        f2 = make_float4(0.0f, 0.0f, 0.0f, 0.0f);
    }
    float4* dst = (float4*)&wsf[W_U + i*12];
    dst[0] = f0; dst[1] = f1; dst[2] = f2;
    wsf[W_KEY + i] = valid ? tz : INFINITY;
    out[O_RADII + i] = valid ? radf : 0.0f;
}

// stable parallel rank sort, one wave (64 threads) per gaussian.
// rank[i] = #{j : key[j]<key[i] or (key[j]==key[i] and j<i)}
__global__ __launch_bounds__(256) void k_rank(float* __restrict__ wsf,
                                              int* __restrict__ wsi,
                                              unsigned* __restrict__ wsu)
{
    __shared__ float sk[NG];
    int tid = threadIdx.x;
    float4* sk4 = (float4*)sk;
    const float4* gk4 = (const float4*)(wsf + W_KEY);
    sk4[tid]       = gk4[tid];
    sk4[tid + 256] = gk4[tid + 256];
    __syncthreads();

    int i = blockIdx.x * (256 / TPG) + (tid >> 6);
    int s = tid & (TPG - 1);
    float ki = sk[i];

    int r = 0;
    #pragma unroll
    for (int u = 0; u < SEGK / 4; ++u) {
        int j4 = (u + s) & (SEGK / 4 - 1);       // rotate read phase per lane
        float4 kk = sk4[s * (SEGK / 4) + j4];
        int jb = s * SEGK + j4 * 4;
        r += (kk.x < ki || (kk.x == ki && (jb+0) < i)) ? 1 : 0;
        r += (kk.y < ki || (kk.y == ki && (jb+1) < i)) ? 1 : 0;
        r += (kk.z < ki || (kk.z == ki && (jb+2) < i)) ? 1 : 0;
        r += (kk.w < ki || (kk.w == ki && (jb+3) < i)) ? 1 : 0;
    }
    r += __shfl_xor(r, 1);
    r += __shfl_xor(r, 2);
    r += __shfl_xor(r, 4);
    r += __shfl_xor(r, 8);
    r += __shfl_xor(r, 16);
    r += __shfl_xor(r, 32);

    if (s == 0) {
        const float4* src = (const float4*)&wsf[W_U + i*12];
        float4 a0 = src[0], a1 = src[1], a2 = src[2];
        float4* dst = (float4*)&wsf[W_S + r*12];
        dst[0] = a0; dst[1] = a1; dst[2] = a2;
        wsu[W_PB + r] = wsu[W_UPB + i];
        wsi[W_ORG + r] = i;
    }
}

// one wave per (tile, depth-segment). Composites its segment into partials;
// the LAST segment-block to finish a tile folds all NSEG partials and writes
// the final pixels (rocPRIM-style last-block pattern, device-scope fences).
__global__ __launch_bounds__(64) void k_rast(const float* __restrict__ wsf,
                                             const int* __restrict__ wsi,
                                             const unsigned* __restrict__ wsu,
                                             float* __restrict__ part,
                                             int* __restrict__ ctr,
                                             const float* __restrict__ bg,
                                             float* __restrict__ out)
{
    __shared__ int   Llist[SEGS];    // 1 KB
    __shared__ int   Lcnt[SEGS];     // 1 KB
    __shared__ float Ls[64][12];     // 3 KB

    int lane = threadIdx.x;
    int tile = blockIdx.x;
    int seg  = blockIdx.y;
    int tx = tile % TX, ty = tile / TX;
    int base0 = seg * SEGS;

    // ---- scan this segment's packed tile ranges (coalesced uint loads) ----
    int cnt = 0;
    #pragma unroll
    for (int c = 0; c < SEGS / 64; ++c) {
        unsigned w = wsu[W_PB + base0 + c * 64 + lane];
        bool keep = ((w & 255u) <= (unsigned)tx) && ((unsigned)tx <= ((w >> 16) & 255u))
                 && (((w >> 8) & 255u) <= (unsigned)ty) && ((unsigned)ty <= (w >> 24));
        unsigned long long m = __ballot(keep);
        if (keep) Llist[cnt + __popcll(m & ((1ull << lane) - 1ull))] = base0 + c * 64 + lane;
        cnt += (int)__popcll(m);
    }
    __syncthreads();

    // ---- composite: each lane owns one pixel of the 8x8 tile ----
    int px_i = tx * TS + (lane & 7);
    int py_i = ty * TS + (lane >> 3);
    float gx = (float)px_i, gy = (float)py_i;

    float T = 1.0f, C0 = 0.0f, C1 = 0.0f, C2 = 0.0f, D = 0.0f;

    for (int b2 = 0; b2 < cnt; b2 += 64) {
        int cl = min(64, cnt - b2);
        if (lane < cl) {
            int e = Llist[b2 + lane];
            const float4* s4 = (const float4*)&wsf[W_S + e*12];
            *(float4*)&Ls[lane][0] = s4[0];
            *(float4*)&Ls[lane][4] = s4[1];
            *(float4*)&Ls[lane][8] = s4[2];
        }
        __syncthreads();
        #pragma unroll 2
        for (int g = 0; g < cl; ++g) {
            float4 f0 = *(const float4*)&Ls[g][0];   // px, py, (dxm, dym unused)
            float4 f1 = *(const float4*)&Ls[g][4];   // h0, h1, h2, l2op
            float4 f2 = *(const float4*)&Ls[g][8];   // r, g, b, dep
            float dx = f0.x - gx, dy = f0.y - gy;
            float p2 = f1.x*dx*dx + f1.y*dx*dy + f1.z*dy*dy;   // power*log2e (<=0 inside)
            float al = fminf(0.99f, exp2f(p2 + f1.w));
            bool keep = (p2 <= 0.0f) && (al >= A_MIN);
            float a = keep ? al : 0.0f;
            float w = T * a;
            C0 = fmaf(w, f2.x, C0);
            C1 = fmaf(w, f2.y, C1);
            C2 = fmaf(w, f2.z, C2);
            D  = fmaf(w, f2.w, D);
            T -= w;                                   // T *= (1-a)
            unsigned long long m = __ballot(keep);
            if (lane == g) Lcnt[b2 + g] = (int)__popcll(m);
        }
        __syncthreads();
    }

    // ---- publish this segment's partials ----
    float* p = part + (tile * NSEG + seg) * 5 * 64;
    p[0*64 + lane] = T;
    p[1*64 + lane] = C0;
    p[2*64 + lane] = C1;
    p[3*64 + lane] = C2;
    p[4*64 + lane] = D;

    // ---- batched n_touched flush (order-independent exact float atomics) ----
    for (int j = lane; j < cnt; j += 64) {
        int c = Lcnt[j];
        if (c > 0) atomicAdd(out + O_NT + wsi[W_ORG + Llist[j]], (float)c);
    }

    // ---- last block for this tile folds the partials ----
    __threadfence();                               // release: partials visible device-wide
    int old = 0;
    if (lane == 0) old = atomicAdd(ctr + tile, 1); // device-scope by default
    old = __shfl(old, 0);
    if (old == NSEG - 1) {
        __threadfence();                           // acquire: see all segments' partials
        float Tt = 1.0f, c0 = 0.0f, c1 = 0.0f, c2 = 0.0f, d = 0.0f;
        #pragma unroll
        for (int s = 0; s < NSEG; ++s) {
            const float* q = part + (tile * NSEG + s) * 5 * 64;
            c0 = fmaf(Tt, q[1*64 + lane], c0);
            c1 = fmaf(Tt, q[2*64 + lane], c1);
            c2 = fmaf(Tt, q[3*64 + lane], c2);
            d  = fmaf(Tt, q[4*64 + lane], d);
            Tt *= q[0*64 + lane];
        }
        int pix = py_i * IMG_W + px_i;
        out[O_COLOR + 0*HW + pix] = c0 + bg[0] * Tt;
        out[O_COLOR + 1*HW + pix] = c1 + bg[1] * Tt;
        out[O_COLOR + 2*HW + pix] = c2 + bg[2] * Tt;
        out[O_DEPTH + pix] = d;
        out[O_OPAC  + pix] = 1.0f - Tt;
    }
}

extern "C" void kernel_launch(void* const* d_in, const int* in_sizes, int n_in,
                              void* d_out, int out_size, void* d_ws, size_t ws_size,
                              hipStream_t stream)
{
    const float* means3D = (const float*)d_in[0];
    // d_in[1] = means2D (unused)
    const float* opac    = (const float*)d_in[2];
    const float* cols    = (const float*)d_in[3];
    const float* scales  = (const float*)d_in[4];
    const float* rots    = (const float*)d_in[5];
    const float* bg      = (const float*)d_in[6];
    const float* vm      = (const float*)d_in[7];
    float* out = (float*)d_out;
    float* wsf = (float*)d_ws;
    int*   wsi = (int*)d_ws;
    unsigned* wsu = (unsigned*)d_ws;

    hipLaunchKernelGGL(k_pre, dim3(NG / 256), dim3(256), 0, stream,
                       means3D, opac, cols, scales, rots, vm, wsf, wsu, wsi + W_CTR, out);
    hipLaunchKernelGGL(k_rank, dim3(NG / (256 / TPG)), dim3(256), 0, stream, wsf, wsi, wsu);
    hipLaunchKernelGGL(k_rast, dim3(NTILE, NSEG), dim3(64), 0, stream,
                       wsf, wsi, wsu, wsf + W_PART, wsi + W_CTR, bg, out);
}

// Round 7
// 25.093 us; speedup vs baseline: 8.6914x; 4.6735x over previous
//
#include <hip/hip_runtime.h>
#include <math.h>

namespace {

constexpr int NG     = 2048;
constexpr int IMG_H  = 160;
constexpr int IMG_W  = 224;
constexpr int HW     = IMG_H * IMG_W;   // 35840
constexpr int TS     = 8;               // tile size (8x8 px)
constexpr int TX     = IMG_W / TS;      // 28
constexpr int TYN    = IMG_H / TS;      // 20
constexpr int NTILE  = TX * TYN;        // 560

constexpr int NSEG   = 8;               // depth segments (one wave each)
constexpr int SEGS   = NG / NSEG;       // 256 slots per segment

constexpr int PRB    = 64;              // k_prerank blocks
constexpr int OWN    = NG / PRB;        // 32 own gaussians per block

constexpr float TFX   = 0.5774f;
constexpr float TFY   = (float)(0.5774 * 160.0 / 224.0);
constexpr float FXC   = (float)(224.0 / (2.0 * 0.5774));
constexpr float FYC   = (float)(160.0 / (2.0 * (0.5774 * 160.0 / 224.0)));
constexpr float LIMX  = (float)(1.3 * 0.5774);
constexpr float LIMY  = (float)(1.3 * (0.5774 * 160.0 / 224.0));
constexpr float A_MIN = (float)(1.0 / 255.0);
constexpr float NEARP = 0.2f;
constexpr float LOWPASS = 0.3f;
constexpr float L2E   = 1.4426950408889634f;   // log2(e)
constexpr float LN2   = 0.6931471805599453f;
constexpr float L2_255 = 7.994353436858858f;   // log2(255)

// output float offsets (flat, in return order)
constexpr int O_COLOR = 0;
constexpr int O_RADII = 3 * HW;           // 107520
constexpr int O_DEPTH = O_RADII + NG;     // 109568
constexpr int O_OPAC  = O_DEPTH + HW;     // 145408
constexpr int O_NT    = O_OPAC + HW;      // 181248

// workspace offsets (4B units)
constexpr int W_S    = 0;          // sorted AoS, NG*12 floats
constexpr int W_ORG  = 12 * NG;    // int: original index per sorted slot
constexpr int W_PB   = 13 * NG;    // sorted packed tile bbox, NG uints

} // namespace

struct Rec {
    float px, py, dxm, dym;
    float h0, h1, h2, l2op;
    float cr, cg, cb, dep;
    unsigned pbr;
    bool inr;
    float radf;
};

// The full per-gaussian chain. Returns the sort key (valid ? tz : +inf);
// fills *rec with RAW values when FULL (validity gating applied by caller).
template<bool FULL>
__device__ __forceinline__ float g_chain(int i,
        const float* __restrict__ m3, const float* __restrict__ opc,
        const float* __restrict__ co, const float* __restrict__ sc,
        const float* __restrict__ ro, const float* __restrict__ vm,
        Rec* rec)
{
    float R00 = vm[0], R01 = vm[1], R02 = vm[2],  T0 = vm[3];
    float R10 = vm[4], R11 = vm[5], R12 = vm[6],  T1 = vm[7];
    float R20 = vm[8], R21 = vm[9], R22 = vm[10], T2 = vm[11];

    float mx = m3[3*i], my = m3[3*i+1], mz = m3[3*i+2];
    float tx = R00*mx + R01*my + R02*mz + T0;
    float ty = R10*mx + R11*my + R12*mz + T1;
    float tz = R20*mx + R21*my + R22*mz + T2;

    float txz = fminf(LIMX, fmaxf(-LIMX, tx / tz)) * tz;
    float tyz = fminf(LIMY, fmaxf(-LIMY, ty / tz)) * tz;

    float qw = ro[4*i], qx = ro[4*i+1], qy = ro[4*i+2], qz = ro[4*i+3];
    float qn = 1.0f / sqrtf(qw*qw + qx*qx + qy*qy + qz*qz);
    qw *= qn; qx *= qn; qy *= qn; qz *= qn;
    float r00 = 1.0f - 2.0f*(qy*qy + qz*qz), r01 = 2.0f*(qx*qy - qw*qz), r02 = 2.0f*(qx*qz + qw*qy);
    float r10 = 2.0f*(qx*qy + qw*qz), r11 = 1.0f - 2.0f*(qx*qx + qz*qz), r12 = 2.0f*(qy*qz - qw*qx);
    float r20 = 2.0f*(qx*qz - qw*qy), r21 = 2.0f*(qy*qz + qw*qx), r22 = 1.0f - 2.0f*(qx*qx + qy*qy);

    float s0 = sc[3*i];   s0 = s0 * s0;
    float s1 = sc[3*i+1]; s1 = s1 * s1;
    float s2 = sc[3*i+2]; s2 = s2 * s2;

    float S00 = r00*r00*s0 + r01*r01*s1 + r02*r02*s2;
    float S01 = r00*r10*s0 + r01*r11*s1 + r02*r12*s2;
    float S02 = r00*r20*s0 + r01*r21*s1 + r02*r22*s2;
    float S11 = r10*r10*s0 + r11*r11*s1 + r12*r12*s2;
    float S12 = r10*r20*s0 + r11*r21*s1 + r12*r22*s2;
    float S22 = r20*r20*s0 + r21*r21*s1 + r22*r22*s2;

    float j00 = FXC / tz;
    float j02 = -FXC * txz / (tz * tz);
    float j11 = FYC / tz;
    float j12 = -FYC * tyz / (tz * tz);

    float Tm00 = j00*R00 + j02*R20, Tm01 = j00*R01 + j02*R21, Tm02 = j00*R02 + j02*R22;
    float Tm10 = j11*R10 + j12*R20, Tm11 = j11*R11 + j12*R21, Tm12 = j11*R12 + j12*R22;

    float M00 = Tm00*S00 + Tm01*S01 + Tm02*S02;
    float M01 = Tm00*S01 + Tm01*S11 + Tm02*S12;
    float M02 = Tm00*S02 + Tm01*S12 + Tm02*S22;
    float M10 = Tm10*S00 + Tm11*S01 + Tm12*S02;
    float M11 = Tm10*S01 + Tm11*S11 + Tm12*S12;
    float M12 = Tm10*S02 + Tm11*S12 + Tm12*S22;

    float cov00 = M00*Tm00 + M01*Tm01 + M02*Tm02;
    float cov01 = M00*Tm10 + M01*Tm11 + M02*Tm12;
    float cov11 = M10*Tm10 + M11*Tm11 + M12*Tm12;

    float a = cov00 + LOWPASS;
    float b = cov01;
    float c = cov11 + LOWPASS;
    float det = a*c - b*b;

    float mid  = 0.5f * (a + c);
    float lam1 = mid + sqrtf(fmaxf(0.1f, mid*mid - det));
    float radf = ceilf(3.0f * sqrtf(lam1));

    bool valid = (tz > NEARP) && (det > 0.0f) && (radf > 0.0f);

    if constexpr (FULL) {
        float dinv = 1.0f / det;
        float con0 = c * dinv, con1 = -b * dinv, con2 = a * dinv;

        float px = ((tx / (tz * TFX) + 1.0f) * (float)IMG_W - 1.0f) * 0.5f;
        float py = ((ty / (tz * TFY) + 1.0f) * (float)IMG_H - 1.0f) * 0.5f;

        float op   = opc[i];
        float l2op = log2f(op);
        float tlin = fmaxf(0.0f, (l2op + L2_255) * LN2);
        float dxm  = sqrtf(2.0f * tlin * a) * 1.001f + 0.1f;
        float dym  = sqrtf(2.0f * tlin * c) * 1.001f + 0.1f;

        int itx0 = (int)floorf((px - dxm) * (1.0f / TS));
        int itx1 = (int)floorf((px + dxm) * (1.0f / TS));
        int ity0 = (int)floorf((py - dym) * (1.0f / TS));
        int ity1 = (int)floorf((py + dym) * (1.0f / TS));
        rec->inr = !(itx1 < 0 || ity1 < 0 || itx0 >= TX || ity0 >= TYN);
        unsigned a0 = (unsigned)max(itx0, 0);
        unsigned a1 = (unsigned)max(ity0, 0);
        unsigned a2 = (unsigned)min(itx1, TX - 1);
        unsigned a3 = (unsigned)min(ity1, TYN - 1);
        rec->pbr = a0 | (a1 << 8) | (a2 << 16) | (a3 << 24);

        rec->px = px; rec->py = py; rec->dxm = dxm; rec->dym = dym;
        rec->h0 = -0.5f*con0*L2E; rec->h1 = -con1*L2E; rec->h2 = -0.5f*con2*L2E; rec->l2op = l2op;
        rec->cr = co[3*i]; rec->cg = co[3*i+1]; rec->cb = co[3*i+2]; rec->dep = tz;
        rec->radf = radf;
    }
    return valid ? tz : INFINITY;
}

// Fused preprocess + stable rank sort. Each block redundantly computes ALL
// NG keys (deterministic: identical code/inputs), ranks its OWN gaussians
// against the LDS key table, then scatters full records to sorted slots.
__global__ __launch_bounds__(256) void k_prerank(const float* __restrict__ means3D,
                                                 const float* __restrict__ opac,
                                                 const float* __restrict__ cols,
                                                 const float* __restrict__ scales,
                                                 const float* __restrict__ rots,
                                                 const float* __restrict__ vm,
                                                 float* __restrict__ wsf,
                                                 int* __restrict__ wsi,
                                                 unsigned* __restrict__ wsu,
                                                 float* __restrict__ out)
{
    __shared__ float skbuf[NG];
    __shared__ int   rbuf[OWN];

    int tid = threadIdx.x;
    int b   = blockIdx.x;

    // ---- phase A: all 2048 keys (redundant per block, 8 chains/thread) ----
    #pragma unroll 1
    for (int j = 0; j < NG / 256; ++j) {
        int g = tid + 256 * j;
        skbuf[g] = g_chain<false>(g, means3D, opac, cols, scales, rots, vm, nullptr);
    }
    __syncthreads();

    // ---- phase B: wave-parallel stable ranks for own gaussians ----
    int w = tid >> 6, lane = tid & 63;
    const float4* sk4 = (const float4*)skbuf;
    for (int k = 0; k < OWN / 4; ++k) {          // 8 gaussians per wave
        int i = b * OWN + w * (OWN / 4) + k;
        float ki = skbuf[i];
        int r = 0;
        #pragma unroll
        for (int u = 0; u < NG / 256; ++u) {     // 8 float4 reads per lane
            float4 kk = sk4[lane + 64 * u];
            int jb = (lane + 64 * u) * 4;
            r += (kk.x < ki || (kk.x == ki && (jb+0) < i)) ? 1 : 0;
            r += (kk.y < ki || (kk.y == ki && (jb+1) < i)) ? 1 : 0;
            r += (kk.z < ki || (kk.z == ki && (jb+2) < i)) ? 1 : 0;
            r += (kk.w < ki || (kk.w == ki && (jb+3) < i)) ? 1 : 0;
        }
        r += __shfl_xor(r, 1);
        r += __shfl_xor(r, 2);
        r += __shfl_xor(r, 4);
        r += __shfl_xor(r, 8);
        r += __shfl_xor(r, 16);
        r += __shfl_xor(r, 32);
        if (lane == 0) rbuf[w * (OWN / 4) + k] = r;
    }
    __syncthreads();

    // ---- phase C: full record for own gaussians, scatter to sorted slot ----
    if (tid < OWN) {
        int i = b * OWN + tid;
        Rec rec;
        (void)g_chain<true>(i, means3D, opac, cols, scales, rots, vm, &rec);
        bool valid = (skbuf[i] < INFINITY);      // authoritative (matches ranking)
        int r = rbuf[tid];

        float4 f0 = valid ? make_float4(rec.px, rec.py, rec.dxm, rec.dym)
                          : make_float4(1e9f, 1e9f, -1.0f, -1.0f);
        float4 f1 = valid ? make_float4(rec.h0, rec.h1, rec.h2, rec.l2op)
                          : make_float4(0.0f, 0.0f, 0.0f, -1000.0f);
        float4 f2 = valid ? make_float4(rec.cr, rec.cg, rec.cb, rec.dep)
                          : make_float4(0.0f, 0.0f, 0.0f, 0.0f);
        float4* dst = (float4*)&wsf[W_S + r*12];
        dst[0] = f0; dst[1] = f1; dst[2] = f2;
        wsu[W_PB + r]  = (valid && rec.inr) ? rec.pbr : 0xFFFFFFFFu;
        wsi[W_ORG + r] = i;
        out[O_RADII + i] = valid ? rec.radf : 0.0f;
        out[O_NT + i] = 0.0f;                    // re-zeroed every call
    }
}

// One block per tile; wave wv composites depth-segment wv; in-block combine.
__global__ __launch_bounds__(512) void k_rast(const float* __restrict__ wsf,
                                              const int* __restrict__ wsi,
                                              const unsigned* __restrict__ wsu,
                                              const float* __restrict__ bg,
                                              float* __restrict__ out)
{
    __shared__ int   Llist[NSEG][SEGS];   // 8 KB
    __shared__ int   Lcnt[NSEG][SEGS];    // 8 KB
    __shared__ float Ls[NSEG][64][12];    // 24 KB
    __shared__ float Lpart[NSEG][5][64];  // 10 KB

    int tid  = threadIdx.x;
    int lane = tid & 63;
    int wv   = tid >> 6;
    int tile = blockIdx.x;
    int tx = tile % TX, ty = tile / TX;
    int base0 = wv * SEGS;

    // ---- scan this segment's packed tile ranges (ballot-compact, order kept) ----
    int cnt = 0;
    #pragma unroll
    for (int c = 0; c < SEGS / 64; ++c) {
        unsigned w = wsu[W_PB + base0 + c * 64 + lane];
        bool keep = ((w & 255u) <= (unsigned)tx) && ((unsigned)tx <= ((w >> 16) & 255u))
                 && (((w >> 8) & 255u) <= (unsigned)ty) && ((unsigned)ty <= (w >> 24));
        unsigned long long m = __ballot(keep);
        if (keep) Llist[wv][cnt + __popcll(m & ((1ull << lane) - 1ull))] = base0 + c * 64 + lane;
        cnt += (int)__popcll(m);
    }

    // ---- composite: each lane owns one pixel of the 8x8 tile ----
    int px_i = tx * TS + (lane & 7);
    int py_i = ty * TS + (lane >> 3);
    float gx = (float)px_i, gy = (float)py_i;

    float T = 1.0f, C0 = 0.0f, C1 = 0.0f, C2 = 0.0f, D = 0.0f;

    for (int b2 = 0; b2 < cnt; b2 += 64) {
        int cl = min(64, cnt - b2);
        if (lane < cl) {
            int e = Llist[wv][b2 + lane];
            const float4* s4 = (const float4*)&wsf[W_S + e*12];
            *(float4*)&Ls[wv][lane][0] = s4[0];
            *(float4*)&Ls[wv][lane][4] = s4[1];
            *(float4*)&Ls[wv][lane][8] = s4[2];
        }
        #pragma unroll 2
        for (int g = 0; g < cl; ++g) {
            float4 f0 = *(const float4*)&Ls[wv][g][0];   // px, py, (dxm, dym)
            float4 f1 = *(const float4*)&Ls[wv][g][4];   // h0, h1, h2, l2op
            float4 f2 = *(const float4*)&Ls[wv][g][8];   // r, g, b, dep
            float dx = f0.x - gx, dy = f0.y - gy;
            float p2 = f1.x*dx*dx + f1.y*dx*dy + f1.z*dy*dy;   // power*log2e
            float al = fminf(0.99f, exp2f(p2 + f1.w));
            bool keep = (p2 <= 0.0f) && (al >= A_MIN);
            float a = keep ? al : 0.0f;
            float w = T * a;
            C0 = fmaf(w, f2.x, C0);
            C1 = fmaf(w, f2.y, C1);
            C2 = fmaf(w, f2.z, C2);
            D  = fmaf(w, f2.w, D);
            T -= w;                                   // T *= (1-a)
            unsigned long long m = __ballot(keep);
            if (lane == g) Lcnt[wv][b2 + g] = (int)__popcll(m);
        }
    }

    Lpart[wv][0][lane] = T;
    Lpart[wv][1][lane] = C0;
    Lpart[wv][2][lane] = C1;
    Lpart[wv][3][lane] = C2;
    Lpart[wv][4][lane] = D;

    // ---- batched n_touched flush (order-independent exact float atomics) ----
    for (int j = lane; j < cnt; j += 64) {
        int c = Lcnt[wv][j];
        if (c > 0) atomicAdd(out + O_NT + wsi[W_ORG + Llist[wv][j]], (float)c);
    }

    __syncthreads();

    // ---- in-block combine (wave 0), depth order over segments ----
    if (wv == 0) {
        float Tt = 1.0f, c0 = 0.0f, c1 = 0.0f, c2 = 0.0f, d = 0.0f;
        #pragma unroll
        for (int s = 0; s < NSEG; ++s) {
            c0 = fmaf(Tt, Lpart[s][1][lane], c0);
            c1 = fmaf(Tt, Lpart[s][2][lane], c1);
            c2 = fmaf(Tt, Lpart[s][3][lane], c2);
            d  = fmaf(Tt, Lpart[s][4][lane], d);
            Tt *= Lpart[s][0][lane];
        }
        int pix = py_i * IMG_W + px_i;
        out[O_COLOR + 0*HW + pix] = c0 + bg[0] * Tt;
        out[O_COLOR + 1*HW + pix] = c1 + bg[1] * Tt;
        out[O_COLOR + 2*HW + pix] = c2 + bg[2] * Tt;
        out[O_DEPTH + pix] = d;
        out[O_OPAC  + pix] = 1.0f - Tt;
    }
}

extern "C" void kernel_launch(void* const* d_in, const int* in_sizes, int n_in,
                              void* d_out, int out_size, void* d_ws, size_t ws_size,
                              hipStream_t stream)
{
    const float* means3D = (const float*)d_in[0];
    // d_in[1] = means2D (unused)
    const float* opac    = (const float*)d_in[2];
    const float* cols    = (const float*)d_in[3];
    const float* scales  = (const float*)d_in[4];
    const float* rots    = (const float*)d_in[5];
    const float* bg      = (const float*)d_in[6];
    const float* vm      = (const float*)d_in[7];
    float* out = (float*)d_out;
    float* wsf = (float*)d_ws;
    int*   wsi = (int*)d_ws;
    unsigned* wsu = (unsigned*)d_ws;

    hipLaunchKernelGGL(k_prerank, dim3(PRB), dim3(256), 0, stream,
                       means3D, opac, cols, scales, rots, vm, wsf, wsi, wsu, out);
    hipLaunchKernelGGL(k_rast, dim3(NTILE), dim3(512), 0, stream,
                       wsf, wsi, wsu, bg, out);
}

// Round 8
// 19.511 us; speedup vs baseline: 11.1782x; 1.2861x over previous
//
#include <hip/hip_runtime.h>
#include <math.h>

namespace {

constexpr int NG     = 2048;
constexpr int IMG_H  = 160;
constexpr int IMG_W  = 224;
constexpr int HW     = IMG_H * IMG_W;   // 35840
constexpr int TS     = 8;               // tile size (8x8 px)
constexpr int TX     = IMG_W / TS;      // 28
constexpr int TYN    = IMG_H / TS;      // 20
constexpr int NTILE  = TX * TYN;        // 560

constexpr int NSEG   = 8;               // depth segments (one wave each)
constexpr int SEGS   = NG / NSEG;       // 256 slots per segment

constexpr int TPG    = 64;              // k_rank: threads per gaussian (full wave)
constexpr int SEGK   = NG / TPG;        // 32 keys per thread

constexpr float TFX   = 0.5774f;
constexpr float TFY   = (float)(0.5774 * 160.0 / 224.0);
constexpr float FXC   = (float)(224.0 / (2.0 * 0.5774));
constexpr float FYC   = (float)(160.0 / (2.0 * (0.5774 * 160.0 / 224.0)));
constexpr float LIMX  = (float)(1.3 * 0.5774);
constexpr float LIMY  = (float)(1.3 * (0.5774 * 160.0 / 224.0));
constexpr float A_MIN = (float)(1.0 / 255.0);
constexpr float NEARP = 0.2f;
constexpr float LOWPASS = 0.3f;
constexpr float L2E   = 1.4426950408889634f;   // log2(e)
constexpr float LN2   = 0.6931471805599453f;
constexpr float L2_255 = 7.994353436858858f;   // log2(255)

// output float offsets (flat, in return order)
constexpr int O_COLOR = 0;
constexpr int O_RADII = 3 * HW;           // 107520
constexpr int O_DEPTH = O_RADII + NG;     // 109568
constexpr int O_OPAC  = O_DEPTH + HW;     // 145408
constexpr int O_NT    = O_OPAC + HW;      // 181248

// workspace offsets (4B units)
// AoS record (12 floats): [0]px [1]py [2]dxm [3]dym | [4]h0 [5]h1 [6]h2 [7]l2op | [8]r [9]g [10]b [11]dep
constexpr int W_U    = 0;          // unsorted AoS, NG*12 floats
constexpr int W_KEY  = 12 * NG;    // depth keys, NG floats
constexpr int W_UPB  = 13 * NG;    // unsorted packed tile bbox, NG uints
constexpr int W_S    = 14 * NG;    // sorted AoS, NG*12 floats
constexpr int W_ORG  = 26 * NG;    // int: original index per sorted slot
constexpr int W_PB   = 27 * NG;    // sorted packed tile bbox, NG uints

} // namespace

__global__ __launch_bounds__(256) void k_pre(const float* __restrict__ means3D,
                                             const float* __restrict__ opac,
                                             const float* __restrict__ cols,
                                             const float* __restrict__ scales,
                                             const float* __restrict__ rots,
                                             const float* __restrict__ vm,
                                             float* __restrict__ wsf,
                                             unsigned* __restrict__ wsu,
                                             float* __restrict__ out)
{
    int i = blockIdx.x * blockDim.x + threadIdx.x;
    if (i >= NG) return;
    out[O_NT + i] = 0.0f;   // n_touched accumulator (re-zeroed every call)

    float R00 = vm[0], R01 = vm[1], R02 = vm[2],  T0 = vm[3];
    float R10 = vm[4], R11 = vm[5], R12 = vm[6],  T1 = vm[7];
    float R20 = vm[8], R21 = vm[9], R22 = vm[10], T2 = vm[11];

    float mx = means3D[3*i], my = means3D[3*i+1], mz = means3D[3*i+2];
    float tx = R00*mx + R01*my + R02*mz + T0;
    float ty = R10*mx + R11*my + R12*mz + T1;
    float tz = R20*mx + R21*my + R22*mz + T2;

    float txz = fminf(LIMX, fmaxf(-LIMX, tx / tz)) * tz;
    float tyz = fminf(LIMY, fmaxf(-LIMY, ty / tz)) * tz;

    float qw = rots[4*i], qx = rots[4*i+1], qy = rots[4*i+2], qz = rots[4*i+3];
    float qn = 1.0f / sqrtf(qw*qw + qx*qx + qy*qy + qz*qz);
    qw *= qn; qx *= qn; qy *= qn; qz *= qn;
    float r00 = 1.0f - 2.0f*(qy*qy + qz*qz), r01 = 2.0f*(qx*qy - qw*qz), r02 = 2.0f*(qx*qz + qw*qy);
    float r10 = 2.0f*(qx*qy + qw*qz), r11 = 1.0f - 2.0f*(qx*qx + qz*qz), r12 = 2.0f*(qy*qz - qw*qx);
    float r20 = 2.0f*(qx*qz - qw*qy), r21 = 2.0f*(qy*qz + qw*qx), r22 = 1.0f - 2.0f*(qx*qx + qy*qy);

    float s0 = scales[3*i];   s0 = s0 * s0;
    float s1 = scales[3*i+1]; s1 = s1 * s1;
    float s2 = scales[3*i+2]; s2 = s2 * s2;

    float S00 = r00*r00*s0 + r01*r01*s1 + r02*r02*s2;
    float S01 = r00*r10*s0 + r01*r11*s1 + r02*r12*s2;
    float S02 = r00*r20*s0 + r01*r21*s1 + r02*r22*s2;
    float S11 = r10*r10*s0 + r11*r11*s1 + r12*r12*s2;
    float S12 = r10*r20*s0 + r11*r21*s1 + r12*r22*s2;
    float S22 = r20*r20*s0 + r21*r21*s1 + r22*r22*s2;

    float j00 = FXC / tz;
    float j02 = -FXC * txz / (tz * tz);
    float j11 = FYC / tz;
    float j12 = -FYC * tyz / (tz * tz);

    float Tm00 = j00*R00 + j02*R20, Tm01 = j00*R01 + j02*R21, Tm02 = j00*R02 + j02*R22;
    float Tm10 = j11*R10 + j12*R20, Tm11 = j11*R11 + j12*R21, Tm12 = j11*R12 + j12*R22;

    float M00 = Tm00*S00 + Tm01*S01 + Tm02*S02;
    float M01 = Tm00*S01 + Tm01*S11 + Tm02*S12;
    float M02 = Tm00*S02 + Tm01*S12 + Tm02*S22;
    float M10 = Tm10*S00 + Tm11*S01 + Tm12*S02;
    float M11 = Tm10*S01 + Tm11*S11 + Tm12*S12;
    float M12 = Tm10*S02 + Tm11*S12 + Tm12*S22;

    float cov00 = M00*Tm00 + M01*Tm01 + M02*Tm02;
    float cov01 = M00*Tm10 + M01*Tm11 + M02*Tm12;
    float cov11 = M10*Tm10 + M11*Tm11 + M12*Tm12;

    float a = cov00 + LOWPASS;
    float b = cov01;
    float c = cov11 + LOWPASS;
    float det = a*c - b*b;
    float dinv = 1.0f / det;
    float con0 = c * dinv, con1 = -b * dinv, con2 = a * dinv;

    float mid  = 0.5f * (a + c);
    float lam1 = mid + sqrtf(fmaxf(0.1f, mid*mid - det));
    float radf = ceilf(3.0f * sqrtf(lam1));

    float px = ((tx / (tz * TFX) + 1.0f) * (float)IMG_W - 1.0f) * 0.5f;
    float py = ((ty / (tz * TFY) + 1.0f) * (float)IMG_H - 1.0f) * 0.5f;

    bool valid = (tz > NEARP) && (det > 0.0f) && (radf > 0.0f);

    float op   = opac[i];
    float l2op = log2f(op);
    // exact alpha-cutoff ellipse: alpha>=1/255 <=> power >= -ln(255*op); bbox half-widths
    float tlin = fmaxf(0.0f, (l2op + L2_255) * LN2);
    float dxm  = sqrtf(2.0f * tlin * a) * 1.001f + 0.1f;
    float dym  = sqrtf(2.0f * tlin * c) * 1.001f + 0.1f;

    // packed conservative tile range (uchar4: tx0, ty0, tx1, ty1)
    int itx0 = (int)floorf((px - dxm) * (1.0f / TS));
    int itx1 = (int)floorf((px + dxm) * (1.0f / TS));
    int ity0 = (int)floorf((py - dym) * (1.0f / TS));
    int ity1 = (int)floorf((py + dym) * (1.0f / TS));
    unsigned pb;
    if (!valid || itx1 < 0 || ity1 < 0 || itx0 >= TX || ity0 >= TYN) {
        pb = 0xFFFFFFFFu;   // empty: tx0=255 never <= tx
    } else {
        unsigned a0 = (unsigned)max(itx0, 0);
        unsigned a1 = (unsigned)max(ity0, 0);
        unsigned a2 = (unsigned)min(itx1, TX - 1);
        unsigned a3 = (unsigned)min(ity1, TYN - 1);
        pb = a0 | (a1 << 8) | (a2 << 16) | (a3 << 24);
    }
    wsu[W_UPB + i] = pb;

    float4 f0, f1, f2;
    if (valid) {
        f0 = make_float4(px, py, dxm, dym);
        f1 = make_float4(-0.5f*con0*L2E, -con1*L2E, -0.5f*con2*L2E, l2op);
        f2 = make_float4(cols[3*i], cols[3*i+1], cols[3*i+2], tz);
    } else {
        f0 = make_float4(1e9f, 1e9f, -1.0f, -1.0f);
        f1 = make_float4(0.0f, 0.0f, 0.0f, -1000.0f);
        f2 = make_float4(0.0f, 0.0f, 0.0f, 0.0f);
    }
    float4* dst = (float4*)&wsf[W_U + i*12];
    dst[0] = f0; dst[1] = f1; dst[2] = f2;
    wsf[W_KEY + i] = valid ? tz : INFINITY;
    out[O_RADII + i] = valid ? radf : 0.0f;
}

// stable parallel rank sort, one wave (64 threads) per gaussian.
// rank[i] = #{j : key[j]<key[i] or (key[j]==key[i] and j<i)}
__global__ __launch_bounds__(256) void k_rank(float* __restrict__ wsf,
                                              int* __restrict__ wsi,
                                              unsigned* __restrict__ wsu)
{
    __shared__ float sk[NG];
    int tid = threadIdx.x;
    float4* sk4 = (float4*)sk;
    const float4* gk4 = (const float4*)(wsf + W_KEY);
    sk4[tid]       = gk4[tid];
    sk4[tid + 256] = gk4[tid + 256];
    __syncthreads();

    int i = blockIdx.x * (256 / TPG) + (tid >> 6);
    int s = tid & (TPG - 1);
    float ki = sk[i];

    int r = 0;
    #pragma unroll
    for (int u = 0; u < SEGK / 4; ++u) {
        int j4 = (u + s) & (SEGK / 4 - 1);       // rotate read phase per lane
        float4 kk = sk4[s * (SEGK / 4) + j4];
        int jb = s * SEGK + j4 * 4;
        r += (kk.x < ki || (kk.x == ki && (jb+0) < i)) ? 1 : 0;
        r += (kk.y < ki || (kk.y == ki && (jb+1) < i)) ? 1 : 0;
        r += (kk.z < ki || (kk.z == ki && (jb+2) < i)) ? 1 : 0;
        r += (kk.w < ki || (kk.w == ki && (jb+3) < i)) ? 1 : 0;
    }
    r += __shfl_xor(r, 1);
    r += __shfl_xor(r, 2);
    r += __shfl_xor(r, 4);
    r += __shfl_xor(r, 8);
    r += __shfl_xor(r, 16);
    r += __shfl_xor(r, 32);

    if (s == 0) {
        const float4* src = (const float4*)&wsf[W_U + i*12];
        float4 a0 = src[0], a1 = src[1], a2 = src[2];
        float4* dst = (float4*)&wsf[W_S + r*12];
        dst[0] = a0; dst[1] = a1; dst[2] = a2;
        wsu[W_PB + r] = wsu[W_UPB + i];
        wsi[W_ORG + r] = i;
    }
}

// One block per tile; wave wv composites depth-segment wv; in-block combine.
__global__ __launch_bounds__(512) void k_rast(const float* __restrict__ wsf,
                                              const int* __restrict__ wsi,
                                              const unsigned* __restrict__ wsu,
                                              const float* __restrict__ bg,
                                              float* __restrict__ out)
{
    __shared__ int   Llist[NSEG][SEGS];   // 8 KB
    __shared__ int   Lcnt[NSEG][SEGS];    // 8 KB
    __shared__ float Ls[NSEG][64][12];    // 24 KB
    __shared__ float Lpart[NSEG][5][64];  // 10 KB

    int tid  = threadIdx.x;
    int lane = tid & 63;
    int wv   = tid >> 6;
    int tile = blockIdx.x;
    int tx = tile % TX, ty = tile / TX;
    int base0 = wv * SEGS;

    // ---- scan this segment's packed tile ranges (ballot-compact, order kept) ----
    int cnt = 0;
    #pragma unroll
    for (int c = 0; c < SEGS / 64; ++c) {
        unsigned w = wsu[W_PB + base0 + c * 64 + lane];
        bool keep = ((w & 255u) <= (unsigned)tx) && ((unsigned)tx <= ((w >> 16) & 255u))
                 && (((w >> 8) & 255u) <= (unsigned)ty) && ((unsigned)ty <= (w >> 24));
        unsigned long long m = __ballot(keep);
        if (keep) Llist[wv][cnt + __popcll(m & ((1ull << lane) - 1ull))] = base0 + c * 64 + lane;
        cnt += (int)__popcll(m);
    }

    // ---- composite: each lane owns one pixel of the 8x8 tile ----
    int px_i = tx * TS + (lane & 7);
    int py_i = ty * TS + (lane >> 3);
    float gx = (float)px_i, gy = (float)py_i;

    float T = 1.0f, C0 = 0.0f, C1 = 0.0f, C2 = 0.0f, D = 0.0f;

    for (int b2 = 0; b2 < cnt; b2 += 64) {
        int cl = min(64, cnt - b2);
        if (lane < cl) {
            int e = Llist[wv][b2 + lane];
            const float4* s4 = (const float4*)&wsf[W_S + e*12];
            *(float4*)&Ls[wv][lane][0] = s4[0];
            *(float4*)&Ls[wv][lane][4] = s4[1];
            *(float4*)&Ls[wv][lane][8] = s4[2];
        }
        #pragma unroll 2
        for (int g = 0; g < cl; ++g) {
            float4 f0 = *(const float4*)&Ls[wv][g][0];   // px, py, (dxm, dym)
            float4 f1 = *(const float4*)&Ls[wv][g][4];   // h0, h1, h2, l2op
            float4 f2 = *(const float4*)&Ls[wv][g][8];   // r, g, b, dep
            float dx = f0.x - gx, dy = f0.y - gy;
            float p2 = f1.x*dx*dx + f1.y*dx*dy + f1.z*dy*dy;   // power*log2e
            float al = fminf(0.99f, exp2f(p2 + f1.w));
            bool keep = (p2 <= 0.0f) && (al >= A_MIN);
            float a = keep ? al : 0.0f;
            float w = T * a;
            C0 = fmaf(w, f2.x, C0);
            C1 = fmaf(w, f2.y, C1);
            C2 = fmaf(w, f2.z, C2);
            D  = fmaf(w, f2.w, D);
            T -= w;                                   // T *= (1-a)
            unsigned long long m = __ballot(keep);
            if (lane == g) Lcnt[wv][b2 + g] = (int)__popcll(m);
        }
    }

    Lpart[wv][0][lane] = T;
    Lpart[wv][1][lane] = C0;
    Lpart[wv][2][lane] = C1;
    Lpart[wv][3][lane] = C2;
    Lpart[wv][4][lane] = D;

    // ---- batched n_touched flush (order-independent exact float atomics) ----
    for (int j = lane; j < cnt; j += 64) {
        int c = Lcnt[wv][j];
        if (c > 0) atomicAdd(out + O_NT + wsi[W_ORG + Llist[wv][j]], (float)c);
    }

    __syncthreads();

    // ---- in-block combine (wave 0), depth order over segments ----
    if (wv == 0) {
        float Tt = 1.0f, c0 = 0.0f, c1 = 0.0f, c2 = 0.0f, d = 0.0f;
        #pragma unroll
        for (int s = 0; s < NSEG; ++s) {
            c0 = fmaf(Tt, Lpart[s][1][lane], c0);
            c1 = fmaf(Tt, Lpart[s][2][lane], c1);
            c2 = fmaf(Tt, Lpart[s][3][lane], c2);
            d  = fmaf(Tt, Lpart[s][4][lane], d);
            Tt *= Lpart[s][0][lane];
        }
        int pix = py_i * IMG_W + px_i;
        out[O_COLOR + 0*HW + pix] = c0 + bg[0] * Tt;
        out[O_COLOR + 1*HW + pix] = c1 + bg[1] * Tt;
        out[O_COLOR + 2*HW + pix] = c2 + bg[2] * Tt;
        out[O_DEPTH + pix] = d;
        out[O_OPAC  + pix] = 1.0f - Tt;
    }
}

extern "C" void kernel_launch(void* const* d_in, const int* in_sizes, int n_in,
                              void* d_out, int out_size, void* d_ws, size_t ws_size,
                              hipStream_t stream)
{
    const float* means3D = (const float*)d_in[0];
    // d_in[1] = means2D (unused)
    const float* opac    = (const float*)d_in[2];
    const float* cols    = (const float*)d_in[3];
    const float* scales  = (const float*)d_in[4];
    const float* rots    = (const float*)d_in[5];
    const float* bg      = (const float*)d_in[6];
    const float* vm      = (const float*)d_in[7];
    float* out = (float*)d_out;
    float* wsf = (float*)d_ws;
    int*   wsi = (int*)d_ws;
    unsigned* wsu = (unsigned*)d_ws;

    hipLaunchKernelGGL(k_pre, dim3(NG / 256), dim3(256), 0, stream,
                       means3D, opac, cols, scales, rots, vm, wsf, wsu, out);
    hipLaunchKernelGGL(k_rank, dim3(NG / (256 / TPG)), dim3(256), 0, stream, wsf, wsi, wsu);
    hipLaunchKernelGGL(k_rast, dim3(NTILE), dim3(512), 0, stream,
                       wsf, wsi, wsu, bg, out);
}